// Round 6
// baseline (362.510 us; speedup 1.0000x reference)
//
#include <hip/hip_runtime.h>
#include <hip/hip_fp16.h>

#define B_  32
#define L_  2048
#define H_  512
#define CA  64        // chunk size; 32 serial steps per batch
#define NC  32        // chunks per batch; key row l=2047 zero-padded
#define EPSF 1e-6f

typedef _Float16 f16x8 __attribute__((ext_vector_type(8)));
typedef float f32x16 __attribute__((ext_vector_type(16)));

// ---- wave64 sum reduction via DPP; full sum lands in lane 63 ----
template <int CTRL>
__device__ __forceinline__ float dpp_shift_add(float x) {
  int t = __builtin_amdgcn_update_dpp(0, __float_as_int(x), CTRL, 0xf, 0xf, true);
  return x + __int_as_float(t);
}
__device__ __forceinline__ float wave_reduce_lane63(float x) {
  x = dpp_shift_add<0x111>(x);  // row_shr:1
  x = dpp_shift_add<0x112>(x);  // row_shr:2
  x = dpp_shift_add<0x114>(x);  // row_shr:4
  x = dpp_shift_add<0x118>(x);  // row_shr:8
  x = dpp_shift_add<0x142>(x);  // row_bcast:15
  x = dpp_shift_add<0x143>(x);  // row_bcast:31
  return x;                     // valid in lane 63
}
// sum within each 16-lane DPP row; result valid in lane 15 of each row
__device__ __forceinline__ float row16_reduce(float x) {
  x = dpp_shift_add<0x111>(x);
  x = dpp_shift_add<0x112>(x);
  x = dpp_shift_add<0x114>(x);
  x = dpp_shift_add<0x118>(x);
  return x;
}
__device__ __forceinline__ float rdlane(float v, int l) {
  return __int_as_float(__builtin_amdgcn_readlane(__float_as_int(v), l));
}
__device__ __forceinline__ void unpack8(const uint4& k, float* f) {
  const float2 f0 = __half22float2(*(const __half2*)&k.x);
  const float2 f1 = __half22float2(*(const __half2*)&k.y);
  const float2 f2 = __half22float2(*(const __half2*)&k.z);
  const float2 f3 = __half22float2(*(const __half2*)&k.w);
  f[0] = f0.x; f[1] = f0.y; f[2] = f1.x; f[3] = f1.y;
  f[4] = f2.x; f[5] = f2.y; f[6] = f3.x; f[7] = f3.y;
}
// clamp to fp16-representable range (padded-row diag X = 1/eps = 1e6
// would otherwise become inf -> 0*inf = NaN in the scan)
__device__ __forceinline__ float clamp16(float v) {
  return fminf(fmaxf(v, -65504.f), 65504.f);
}
// async global->LDS, 16B per lane; LDS base must be wave-uniform
__device__ __forceinline__ void load_lds16h(const unsigned short* g, unsigned short* l) {
  __builtin_amdgcn_global_load_lds(
      (const __attribute__((address_space(1))) unsigned int*)(g),
      (__attribute__((address_space(3))) unsigned int*)(l), 16, 0, 0);
}

// Kf LDS layout: row-major 16B granules, XOR-swizzled. u16 index:
#define KFI(row, k8) (((((row) * 64) + (k8)) * 8) ^ (((row) & 7) << 3))

// =====================================================================
// Kernel A: keys->fp16 Kh, Gram via MFMA, X = (D + triu(G,1))^{-1} via
// reg backsubs + Schur. X written as fp16 (tmh), CLAMPED to fp16 range.
// 256 thr, 80 KiB.
// =====================================================================
__global__ __launch_bounds__(256) void
deltarule_gram64(const float* __restrict__ hidden,
                 unsigned short* __restrict__ Kh,
                 unsigned short* __restrict__ tmh, float* __restrict__ dvec) {
  const int cb = blockIdx.x, b = blockIdx.y;
  const int tid = threadIdx.x, lane = tid & 63, wv = tid >> 6;
  __shared__ __align__(16) unsigned short Kf[CA * H_];  // 64 KB fp16, swizzled granules
  __shared__ __align__(16) float G[CA * CA];            // 16 KB

  const int c0 = cb * CA;
  const float* src = hidden + ((size_t)b * L_ + c0) * H_;
  unsigned short* kout = Kh + ((size_t)b * L_ + c0) * H_;
  const bool lastc = (cb == NC - 1);

  // ---- stage + round to fp16 ----
#pragma unroll
  for (int u = 0; u < 16; ++u) {
    const int f8 = u * 256 + tid;
    const int row = f8 >> 6;
    const int colf = (f8 & 63) * 8;
    float4 va = *(const float4*)(src + row * H_ + colf);
    float4 vb = *(const float4*)(src + row * H_ + colf + 4);
    if (lastc && row == CA - 1) {   // zero-pad key row l=2047
      va = make_float4(0.f, 0.f, 0.f, 0.f);
      vb = make_float4(0.f, 0.f, 0.f, 0.f);
    }
    __half2 h0 = __floats2half2_rn(va.x, va.y);
    __half2 h1 = __floats2half2_rn(va.z, va.w);
    __half2 h2 = __floats2half2_rn(vb.x, vb.y);
    __half2 h3 = __floats2half2_rn(vb.z, vb.w);
    uint4 pk = make_uint4(*(unsigned int*)&h0, *(unsigned int*)&h1,
                          *(unsigned int*)&h2, *(unsigned int*)&h3);
    *(uint4*)&Kf[KFI(row, colf >> 3)] = pk;
    *(uint4*)(kout + row * H_ + colf) = pk;
  }
  __syncthreads();

  // ---- Gram via MFMA: waves 0,1,2 -> tiles (0,0),(0,1),(1,1) ----
  if (wv < 3) {
    const int ta = (wv == 2) ? 1 : 0;
    const int tb = (wv == 0) ? 0 : 1;
    const int mrow = 32 * ta + (lane & 31);
    const int nrow = 32 * tb + (lane & 31);
    const int khi = lane >> 5;
    f32x16 acc;
#pragma unroll
    for (int r = 0; r < 16; ++r) acc[r] = 0.f;
#pragma unroll
    for (int kk = 0; kk < 32; ++kk) {
      const int k8 = 2 * kk + khi;
      const f16x8 av = *(const f16x8*)&Kf[KFI(mrow, k8)];
      const f16x8 bv = *(const f16x8*)&Kf[KFI(nrow, k8)];
      acc = __builtin_amdgcn_mfma_f32_32x32x16_f16(av, bv, acc, 0, 0, 0);
    }
#pragma unroll
    for (int r = 0; r < 16; ++r) {
      const int row32 = (r & 3) + 8 * (r >> 2) + 4 * khi;
      G[(32 * ta + row32) * CA + 32 * tb + (lane & 31)] = acc[r];
    }
  }
  __syncthreads();

  // ---- dvec = diag(G)+eps ----
  if (tid < CA) dvec[((size_t)b * NC + cb) * CA + tid] = G[tid * CA + tid] + EPSF;
  __syncthreads();

  // ---- two parallel 32x32 backsubs (regs + readlane) ----
  if (wv < 2) {
    const int off = wv * 32;          // wave0 -> X00, wave1 -> X11
    const int j = lane & 31;
    float Gr[32], X[32];
#pragma unroll
    for (int t = 0; t < 32; ++t) Gr[t] = G[(off + t) * CA + off + j];
#pragma unroll
    for (int t = 31; t >= 0; --t) {
      float i0 = 0.f, i1 = 0.f;
#pragma unroll
      for (int s = t + 1; s < 32; s += 2) i0 = fmaf(rdlane(Gr[t], s), X[s], i0);
#pragma unroll
      for (int s = t + 2; s < 32; s += 2) i1 = fmaf(rdlane(Gr[t], s), X[s], i1);
      X[t] = (((j == t) ? 1.f : 0.f) - (i0 + i1)) / (rdlane(Gr[t], t) + EPSF);
    }
    if (lane < 32) {
#pragma unroll
      for (int t = 0; t < 32; ++t) G[(off + t) * CA + off + j] = X[t];
    }
  }
  __syncthreads();

  // ---- Schur: Z = U12 * X11, then Y = -X00 * Z over the U12 slot ----
  const int zr = tid >> 3;
  const int zc = (tid & 7) * 4;
  float4 zf = make_float4(0.f, 0.f, 0.f, 0.f);
#pragma unroll
  for (int s = 0; s < 32; ++s) {
    const float u = G[zr * CA + 32 + s];
    const float4 xv = *(const float4*)&G[(32 + s) * CA + 32 + zc];
    zf.x = fmaf(u, xv.x, zf.x); zf.y = fmaf(u, xv.y, zf.y);
    zf.z = fmaf(u, xv.z, zf.z); zf.w = fmaf(u, xv.w, zf.w);
  }
  __syncthreads();
  *(float4*)&G[zr * CA + 32 + zc] = zf;
  __syncthreads();
  float4 yf = make_float4(0.f, 0.f, 0.f, 0.f);
#pragma unroll
  for (int s = 0; s < 32; ++s) {
    const float u = G[zr * CA + s];
    const float4 zv = *(const float4*)&G[s * CA + 32 + zc];
    yf.x = fmaf(u, zv.x, yf.x); yf.y = fmaf(u, zv.y, yf.y);
    yf.z = fmaf(u, zv.z, yf.z); yf.w = fmaf(u, zv.w, yf.w);
  }
  __syncthreads();
  *(float4*)&G[zr * CA + 32 + zc] = make_float4(-yf.x, -yf.y, -yf.z, -yf.w);
  __syncthreads();

  // ---- write tmh (fp16) flat[s*64+j] = X[s][j]; lower-left = 0; clamped ----
  unsigned short* tout = tmh + ((size_t)b * NC + cb) * (CA * CA);
#pragma unroll
  for (int v = 0; v < 4; ++v) {
    const int f4 = v * 256 + tid;
    const int s = f4 >> 4;
    const int j4 = (f4 & 15) * 4;
    float4 val;
    if (s >= 32 && j4 < 32) val = make_float4(0.f, 0.f, 0.f, 0.f);
    else                    val = *(const float4*)&G[s * CA + j4];
    const __half2 a  = __floats2half2_rn(clamp16(val.x), clamp16(val.y));
    const __half2 bb = __floats2half2_rn(clamp16(val.z), clamp16(val.w));
    const uint2 pk = make_uint2(*(const unsigned int*)&a, *(const unsigned int*)&bb);
    *(uint2*)(tout + s * CA + j4) = pk;
  }
}

// =====================================================================
// Kernel B v7: dual-pipe ingest scan. 1024 threads (16 waves).
// K rows 0-31: register prefetch (2 rows/wave). K rows 32-63: async DMA
// (global_load_lds) into double-buffered 32KB LDS tile KL. X in fp16.
// Wave wv owns rows {2wv, 2wv+1, 32+2wv, 33+2wv}. sigma via padded Part2
// + DPP row16. Update via two-phase PartU combine (waves 0-3 own quads;
// w-quads published to swizzled Wsw, ctx-quads in registers). 3 barriers.
// =====================================================================
__global__ __launch_bounds__(1024) void
deltarule_scan64d(const float* __restrict__ hidden,
                  const unsigned short* __restrict__ Kh,
                  const float* __restrict__ Wm, const float* __restrict__ bias,
                  const unsigned short* __restrict__ tmh, const float* __restrict__ dvec,
                  float* __restrict__ out) {
  const int b = blockIdx.x, tid = threadIdx.x, lane = tid & 63, wv = tid >> 6;
  __shared__ __align__(16) unsigned short KL[2][32 * H_]; // 64 KB: K rows 32..63, dbuf
  __shared__ __align__(16) float Wsw[H_];          // swizzled w (dot reads)
  __shared__ __align__(16) float Ctx[H_];          // plain ctx (epilogue)
  __shared__ __align__(16) float PartU[16 * 1024]; // 64 KB update partials
  __shared__ float Part2[64 * 17];                 // sigma partials (padded)

  const unsigned short* khb = Kh + (size_t)b * L_ * H_;
  const unsigned short* tmb = tmh + (size_t)b * NC * (CA * CA);
  const float* dvb = dvec + (size_t)b * NC * CA;

  // combine-phase job assignment (waves 0..3):
  // job 0..127 -> w-quad q=job (h=4q..4q+3); job 128..255 -> ctx-quad.
  const int job = 64 * wv + lane;

  // init swizzled w: pi(h) = ((h&4)<<6) + ((h>>3)<<2) + (h&3)
  if (tid < H_) {
    const float q = hidden[((size_t)b * L_ + (L_ - 1)) * H_ + tid];
    const int p = ((tid & 4) << 6) + ((tid >> 3) << 2) + (tid & 3);
    Wsw[p] = q;
  }
  float4 wq4 = make_float4(0.f, 0.f, 0.f, 0.f);
  float4 cq4 = make_float4(0.f, 0.f, 0.f, 0.f);
  if (wv < 2)   // w-quad owners also keep w in registers
    wq4 = *(const float4*)(hidden + ((size_t)b * L_ + (L_ - 1)) * H_ + 4 * job);

  int cmbBase = 0;
  if (wv < 2)                 cmbBase = (job & 1) * 256 + (job >> 1) * 4;
  else if (wv < 4) { const int qc = job - 128;
                     cmbBase = 512 + (qc & 1) * 256 + (qc >> 1) * 4; }

  // ---- preloop: DMA rows 32-63 of chunk NC-1; prefetch reg rows / X / d ----
  {
    const unsigned short* s0 = khb + ((size_t)(NC - 1) * CA + 32) * H_;
#pragma unroll
    for (int u = 0; u < 2; ++u) {
      const int off = (u * 16 + wv) * 512;
      load_lds16h(s0 + off + 8 * lane, &KL[(NC - 1) & 1][off]);
    }
  }
  uint4 kr[2];
  float2 x01, x23;
  float dv;
  {
#pragma unroll
    for (int i = 0; i < 2; ++i)
      kr[i] = *(const uint4*)(khb + ((size_t)(NC - 1) * CA + 2 * wv + i) * H_ + 8 * lane);
    const unsigned short* tp = tmb + (size_t)(NC - 1) * (CA * CA) + lane * CA;
    x01 = __half22float2(*(const __half2*)&tp[2 * wv]);
    x23 = __half22float2(*(const __half2*)&tp[32 + 2 * wv]);
    dv = dvb[(NC - 1) * CA + lane];
  }
  asm volatile("s_waitcnt vmcnt(0) lgkmcnt(0)\n\ts_barrier" ::: "memory");

  for (int c = NC - 1; c >= 0; --c) {
    const int buf = c & 1;

    // ---- prefetch chunk c-1: reg rows + X + d, then DMA rows 32-63 ----
    uint4 kn[2];
    float2 nx01, nx23;
    float dN = 0.f;
    if (c > 0) {
#pragma unroll
      for (int i = 0; i < 2; ++i)
        kn[i] = *(const uint4*)(khb + ((size_t)(c - 1) * CA + 2 * wv + i) * H_ + 8 * lane);
      const unsigned short* tp = tmb + (size_t)(c - 1) * (CA * CA) + lane * CA;
      nx01 = __half22float2(*(const __half2*)&tp[2 * wv]);
      nx23 = __half22float2(*(const __half2*)&tp[32 + 2 * wv]);
      dN = dvb[(c - 1) * CA + lane];
      const unsigned short* s1 = khb + ((size_t)(c - 1) * CA + 32) * H_;
#pragma unroll
      for (int u = 0; u < 2; ++u) {
        const int off = (u * 16 + wv) * 512;
        load_lds16h(s1 + off + 8 * lane, &KL[buf ^ 1][off]);
      }
    }

    // ---- dot: y for rows {2wv, 2wv+1, 32+2wv, 33+2wv} ----
    const float4 wa  = *(const float4*)&Wsw[4 * lane];
    const float4 wb2 = *(const float4*)&Wsw[256 + 4 * lane];
    uint4 klr[2];
    klr[0] = *(const uint4*)&KL[buf][(2 * wv + 0) * H_ + 8 * lane];
    klr[1] = *(const uint4*)&KL[buf][(2 * wv + 1) * H_ + 8 * lane];
    float ysg[4];
#pragma unroll
    for (int i = 0; i < 4; ++i) {
      float kf[8];
      unpack8((i < 2) ? kr[i] : klr[i - 2], kf);
      float p = kf[0] * wa.x;
      p = fmaf(kf[1], wa.y, p);  p = fmaf(kf[2], wa.z, p);
      p = fmaf(kf[3], wa.w, p);  p = fmaf(kf[4], wb2.x, p);
      p = fmaf(kf[5], wb2.y, p); p = fmaf(kf[6], wb2.z, p);
      p = fmaf(kf[7], wb2.w, p);
      p = wave_reduce_lane63(p);
      ysg[i] = rdlane(p, 63);
    }

    // ---- sigma partial: sp[j=lane] = sum_i y[row_i] * X[j][row_i] ----
    float sp = ysg[0] * x01.x;
    sp = fmaf(ysg[1], x01.y, sp);
    sp = fmaf(ysg[2], x23.x, sp);
    sp = fmaf(ysg[3], x23.y, sp);
    Part2[lane * 17 + wv] = sp;
    asm volatile("s_waitcnt lgkmcnt(0)\n\ts_barrier" ::: "memory");  // b1

    // ---- sigma for this wave's 4 rows: group g handles row_g ----
    // row_g = 2wv + (g&1) + 32*(g>>1), g = lane>>4
    {
      const int g = lane >> 4;
      const int rowg = 2 * wv + (g & 1) + 32 * (g >> 1);
      float red = Part2[rowg * 17 + (lane & 15)];
      red = row16_reduce(red);
      const float sg0 = rdlane(red, 15);
      const float sg1 = rdlane(red, 31);
      const float sg2 = rdlane(red, 47);
      const float sg3 = rdlane(red, 63);
      const float sv0 = sg0 * rdlane(dv, 2 * wv + 0);
      const float sv1 = sg1 * rdlane(dv, 2 * wv + 1);
      const float sv2 = sg2 * rdlane(dv, 32 + 2 * wv);
      const float sv3 = sg3 * rdlane(dv, 33 + 2 * wv);

      // ---- full-width update partials in regs, then 4x b128 to PartU ----
      float ws[8] = {0,0,0,0,0,0,0,0}, cs[8] = {0,0,0,0,0,0,0,0};
#pragma unroll
      for (int i = 0; i < 4; ++i) {
        float kf[8];
        unpack8((i < 2) ? kr[i] : klr[i - 2], kf);
        const float sg = (i == 0) ? sg0 : (i == 1) ? sg1 : (i == 2) ? sg2 : sg3;
        const float sv = (i == 0) ? sv0 : (i == 1) ? sv1 : (i == 2) ? sv2 : sv3;
#pragma unroll
        for (int e = 0; e < 8; ++e) {
          ws[e] = fmaf(sg, kf[e], ws[e]);
          cs[e] = fmaf(sv, kf[e], cs[e]);
        }
      }
      float* pw = &PartU[wv * 1024];
      *(float4*)&pw[4 * lane]       = make_float4(ws[0], ws[1], ws[2], ws[3]);
      *(float4*)&pw[256 + 4 * lane] = make_float4(ws[4], ws[5], ws[6], ws[7]);
      *(float4*)&pw[512 + 4 * lane] = make_float4(cs[0], cs[1], cs[2], cs[3]);
      *(float4*)&pw[768 + 4 * lane] = make_float4(cs[4], cs[5], cs[6], cs[7]);
    }
    asm volatile("s_waitcnt lgkmcnt(0)\n\ts_barrier" ::: "memory");  // b2

    // ---- combine in waves 0-3: sum 16 partials per owned quad ----
    if (wv < 4) {
      float4 s = make_float4(0.f, 0.f, 0.f, 0.f);
#pragma unroll
      for (int w2 = 0; w2 < 16; ++w2) {
        const float4 p4 = *(const float4*)&PartU[w2 * 1024 + cmbBase];
        s.x += p4.x; s.y += p4.y; s.z += p4.z; s.w += p4.w;
      }
      if (wv < 2) {   // w-quad: update register copy, publish to Wsw
        wq4.x -= s.x; wq4.y -= s.y; wq4.z -= s.z; wq4.w -= s.w;
        *(float4*)&Wsw[256 * (job & 1) + 4 * (job >> 1)] = wq4;
      } else {        // ctx-quad: accumulate in registers only
        cq4.x += s.x; cq4.y += s.y; cq4.z += s.z; cq4.w += s.w;
      }
    }

    // rotate prefetched regs
    if (c > 0) {
      dv = dN; x01 = nx01; x23 = nx23;
      kr[0] = kn[0]; kr[1] = kn[1];
    }
    asm volatile("s_waitcnt vmcnt(0) lgkmcnt(0)\n\ts_barrier" ::: "memory");  // b3
  }

  // ---- epilogue: out[b] = W @ ctx + bias ----
  if (wv == 2 || wv == 3) {
    const int qc = job - 128;
    *(float4*)&Ctx[4 * qc] = cq4;
  }
  __syncthreads();
  {
    const int o = tid & (H_ - 1);
    const int hf = tid >> 9;
    float acc = 0.f;
    const float* wr = Wm + (size_t)o * H_ + hf * 256;
    const float* cx = &Ctx[hf * 256];
#pragma unroll 8
    for (int i = 0; i < 256; i += 4) {
      const float4 w4 = *(const float4*)(wr + i);
      const float4 cv = *(const float4*)(cx + i);
      acc = fmaf(w4.x, cv.x, acc); acc = fmaf(w4.y, cv.y, acc);
      acc = fmaf(w4.z, cv.z, acc); acc = fmaf(w4.w, cv.w, acc);
    }
    PartU[hf * 512 + o] = acc;
  }
  __syncthreads();
  if (tid < H_) out[(size_t)b * H_ + tid] = PartU[tid] + PartU[512 + tid] + bias[tid];
}

// =====================================================================
extern "C" void kernel_launch(void* const* d_in, const int* in_sizes, int n_in,
                              void* d_out, int out_size, void* d_ws, size_t ws_size,
                              hipStream_t stream) {
  (void)in_sizes; (void)n_in; (void)out_size; (void)ws_size;
  const float* hidden = (const float*)d_in[0];  // (32, 2048, 512) fp32
  const float* Wm     = (const float*)d_in[1];  // (512, 512) fp32
  const float* bias   = (const float*)d_in[2];  // (512,) fp32
  float* out = (float*)d_out;                   // (32, 512) fp32

  // workspace: Kh 64 MB + tmh 8 MB (fp16) + dvec 256 KB
  const size_t szKh = (size_t)B_ * L_ * H_ * sizeof(unsigned short);
  const size_t szTm = (size_t)B_ * NC * CA * CA * sizeof(unsigned short);
  unsigned short* Kh  = (unsigned short*)d_ws;
  unsigned short* tmh = (unsigned short*)((char*)d_ws + szKh);
  float* dvec = (float*)((char*)d_ws + szKh + szTm);

  deltarule_gram64<<<dim3(NC, B_), 256, 0, stream>>>(hidden, Kh, tmh, dvec);
  deltarule_scan64d<<<B_, 1024, 0, stream>>>(hidden, Kh, Wm, bias, tmh, dvec, out);
}

// Round 7
// 318.360 us; speedup vs baseline: 1.1387x; 1.1387x over previous
//
#include <hip/hip_runtime.h>
#include <hip/hip_fp16.h>

#define B_  32
#define L_  2048
#define H_  512
#define CA  64        // chunk size; 32 serial steps per batch
#define NC  32        // chunks per batch; key row l=2047 zero-padded
#define EPSF 1e-6f

typedef _Float16 f16x8 __attribute__((ext_vector_type(8)));
typedef float f32x16 __attribute__((ext_vector_type(16)));

// ---- wave64 sum reduction via DPP; full sum lands in lane 63 ----
template <int CTRL>
__device__ __forceinline__ float dpp_shift_add(float x) {
  int t = __builtin_amdgcn_update_dpp(0, __float_as_int(x), CTRL, 0xf, 0xf, true);
  return x + __int_as_float(t);
}
__device__ __forceinline__ float wave_reduce_lane63(float x) {
  x = dpp_shift_add<0x111>(x);  // row_shr:1
  x = dpp_shift_add<0x112>(x);  // row_shr:2
  x = dpp_shift_add<0x114>(x);  // row_shr:4
  x = dpp_shift_add<0x118>(x);  // row_shr:8
  x = dpp_shift_add<0x142>(x);  // row_bcast:15
  x = dpp_shift_add<0x143>(x);  // row_bcast:31
  return x;                     // valid in lane 63
}
// sum within each 16-lane DPP row; result valid in lane 15 of each row
__device__ __forceinline__ float row16_reduce(float x) {
  x = dpp_shift_add<0x111>(x);
  x = dpp_shift_add<0x112>(x);
  x = dpp_shift_add<0x114>(x);
  x = dpp_shift_add<0x118>(x);
  return x;
}
__device__ __forceinline__ float rdlane(float v, int l) {
  return __int_as_float(__builtin_amdgcn_readlane(__float_as_int(v), l));
}
__device__ __forceinline__ __half2 u2h2(unsigned int u) {
  __half2 h; *(unsigned int*)&h = u; return h;
}
__device__ __forceinline__ unsigned int h22u(__half2 h) {
  return *(unsigned int*)&h;
}

// Kf LDS layout: row-major 16B granules, XOR-swizzled. u16 index:
#define KFI(row, k8) (((((row) * 64) + (k8)) * 8) ^ (((row) & 7) << 3))

// =====================================================================
// Kernel A (round-4 version, fp32 tmT): keys->fp16 Kh, Gram via MFMA,
// X = (D + triu(G,1))^{-1} via reg backsubs + Schur. 256 thr, 80 KiB.
// =====================================================================
__global__ __launch_bounds__(256) void
deltarule_gram64(const float* __restrict__ hidden,
                 unsigned short* __restrict__ Kh,
                 float* __restrict__ tmT, float* __restrict__ dvec) {
  const int cb = blockIdx.x, b = blockIdx.y;
  const int tid = threadIdx.x, lane = tid & 63, wv = tid >> 6;
  __shared__ __align__(16) unsigned short Kf[CA * H_];  // 64 KB fp16, swizzled granules
  __shared__ __align__(16) float G[CA * CA];            // 16 KB

  const int c0 = cb * CA;
  const float* src = hidden + ((size_t)b * L_ + c0) * H_;
  unsigned short* kout = Kh + ((size_t)b * L_ + c0) * H_;
  const bool lastc = (cb == NC - 1);

  // ---- stage + round to fp16 ----
#pragma unroll
  for (int u = 0; u < 16; ++u) {
    const int f8 = u * 256 + tid;
    const int row = f8 >> 6;
    const int colf = (f8 & 63) * 8;
    float4 va = *(const float4*)(src + row * H_ + colf);
    float4 vb = *(const float4*)(src + row * H_ + colf + 4);
    if (lastc && row == CA - 1) {   // zero-pad key row l=2047
      va = make_float4(0.f, 0.f, 0.f, 0.f);
      vb = make_float4(0.f, 0.f, 0.f, 0.f);
    }
    __half2 h0 = __floats2half2_rn(va.x, va.y);
    __half2 h1 = __floats2half2_rn(va.z, va.w);
    __half2 h2 = __floats2half2_rn(vb.x, vb.y);
    __half2 h3 = __floats2half2_rn(vb.z, vb.w);
    uint4 pk = make_uint4(*(unsigned int*)&h0, *(unsigned int*)&h1,
                          *(unsigned int*)&h2, *(unsigned int*)&h3);
    *(uint4*)&Kf[KFI(row, colf >> 3)] = pk;
    *(uint4*)(kout + row * H_ + colf) = pk;
  }
  __syncthreads();

  // ---- Gram via MFMA: waves 0,1,2 -> tiles (0,0),(0,1),(1,1) ----
  if (wv < 3) {
    const int ta = (wv == 2) ? 1 : 0;
    const int tb = (wv == 0) ? 0 : 1;
    const int mrow = 32 * ta + (lane & 31);
    const int nrow = 32 * tb + (lane & 31);
    const int khi = lane >> 5;
    f32x16 acc;
#pragma unroll
    for (int r = 0; r < 16; ++r) acc[r] = 0.f;
#pragma unroll
    for (int kk = 0; kk < 32; ++kk) {
      const int k8 = 2 * kk + khi;
      const f16x8 av = *(const f16x8*)&Kf[KFI(mrow, k8)];
      const f16x8 bv = *(const f16x8*)&Kf[KFI(nrow, k8)];
      acc = __builtin_amdgcn_mfma_f32_32x32x16_f16(av, bv, acc, 0, 0, 0);
    }
#pragma unroll
    for (int r = 0; r < 16; ++r) {
      const int row32 = (r & 3) + 8 * (r >> 2) + 4 * khi;
      G[(32 * ta + row32) * CA + 32 * tb + (lane & 31)] = acc[r];
    }
  }
  __syncthreads();

  // ---- dvec = diag(G)+eps ----
  if (tid < CA) dvec[((size_t)b * NC + cb) * CA + tid] = G[tid * CA + tid] + EPSF;
  __syncthreads();

  // ---- two parallel 32x32 backsubs (regs + readlane) ----
  if (wv < 2) {
    const int off = wv * 32;          // wave0 -> X00, wave1 -> X11
    const int j = lane & 31;
    float Gr[32], X[32];
#pragma unroll
    for (int t = 0; t < 32; ++t) Gr[t] = G[(off + t) * CA + off + j];
#pragma unroll
    for (int t = 31; t >= 0; --t) {
      float i0 = 0.f, i1 = 0.f;
#pragma unroll
      for (int s = t + 1; s < 32; s += 2) i0 = fmaf(rdlane(Gr[t], s), X[s], i0);
#pragma unroll
      for (int s = t + 2; s < 32; s += 2) i1 = fmaf(rdlane(Gr[t], s), X[s], i1);
      X[t] = (((j == t) ? 1.f : 0.f) - (i0 + i1)) / (rdlane(Gr[t], t) + EPSF);
    }
    if (lane < 32) {
#pragma unroll
      for (int t = 0; t < 32; ++t) G[(off + t) * CA + off + j] = X[t];
    }
  }
  __syncthreads();

  // ---- Schur: Z = U12 * X11, then Y = -X00 * Z over the U12 slot ----
  const int zr = tid >> 3;
  const int zc = (tid & 7) * 4;
  float4 zf = make_float4(0.f, 0.f, 0.f, 0.f);
#pragma unroll
  for (int s = 0; s < 32; ++s) {
    const float u = G[zr * CA + 32 + s];
    const float4 xv = *(const float4*)&G[(32 + s) * CA + 32 + zc];
    zf.x = fmaf(u, xv.x, zf.x); zf.y = fmaf(u, xv.y, zf.y);
    zf.z = fmaf(u, xv.z, zf.z); zf.w = fmaf(u, xv.w, zf.w);
  }
  __syncthreads();
  *(float4*)&G[zr * CA + 32 + zc] = zf;
  __syncthreads();
  float4 yf = make_float4(0.f, 0.f, 0.f, 0.f);
#pragma unroll
  for (int s = 0; s < 32; ++s) {
    const float u = G[zr * CA + s];
    const float4 zv = *(const float4*)&G[s * CA + 32 + zc];
    yf.x = fmaf(u, zv.x, yf.x); yf.y = fmaf(u, zv.y, yf.y);
    yf.z = fmaf(u, zv.z, yf.z); yf.w = fmaf(u, zv.w, yf.w);
  }
  __syncthreads();
  *(float4*)&G[zr * CA + 32 + zc] = make_float4(-yf.x, -yf.y, -yf.z, -yf.w);
  __syncthreads();

  // ---- write tmT (fp32) flat[s*64+j] = X[s][j]; lower-left block = 0 ----
  float* tout = tmT + ((size_t)b * NC + cb) * (CA * CA);
#pragma unroll
  for (int v = 0; v < 4; ++v) {
    const int f4 = v * 256 + tid;
    const int s = f4 >> 4;
    const int j4 = (f4 & 15) * 4;
    float4 val;
    if (s >= 32 && j4 < 32) val = make_float4(0.f, 0.f, 0.f, 0.f);
    else                    val = *(const float4*)&G[s * CA + j4];
    *(float4*)(tout + s * CA + j4) = val;
  }
}

// =====================================================================
// Kernel B v8: packed-fp16 register scan. 1024 threads (16 waves).
// Wave wv owns key rows 4wv..4wv+3 in VGPRs (global prefetch). w lives in
// LDS as packed fp16 (plain order; lane's 8 elems = one b128) with an f32
// master copy in waves 0-3 registers. Dot/update use v_pk_fma_f16
// (__hfma2); cross-lane reduce stays f32 DPP. Partials are packed fp16
// (1KB/wave), combined conflict-free: waves 0-3 -> w, waves 4-7 -> ctx
// (f32 register accumulators). 3 barriers/step.
// =====================================================================
__global__ __launch_bounds__(1024) void
deltarule_scan16(const float* __restrict__ hidden,
                 const unsigned short* __restrict__ Kh,
                 const float* __restrict__ Wm, const float* __restrict__ bias,
                 const float* __restrict__ tmT, const float* __restrict__ dvec,
                 float* __restrict__ out) {
  const int b = blockIdx.x, tid = threadIdx.x, lane = tid & 63, wv = tid >> 6;
  __shared__ __align__(16) unsigned int PartU16[16][512]; // 32 KB: [256 w-words | 256 c-words]
  __shared__ __align__(16) unsigned int Wsw16[256];       // packed fp16 w (plain order)
  __shared__ __align__(16) float Ctx[H_];                 // f32 ctx (epilogue)
  __shared__ float Part2[64 * 17];                        // f32 sigma partials (padded)

  const unsigned short* khb = Kh + (size_t)b * L_ * H_;
  const float* tmb = tmT + (size_t)b * NC * (CA * CA);
  const float* dvb = dvec + (size_t)b * NC * CA;

  const int t256 = 64 * (wv & 3) + lane;   // 0..255 within each 4-wave group

  // ---- init: pack q into Wsw16; f32 master in waves 0-3 ----
  if (tid < 256) {
    const float2 q = *(const float2*)(hidden + ((size_t)b * L_ + (L_ - 1)) * H_ + 2 * tid);
    Wsw16[tid] = h22u(__floats2half2_rn(q.x, q.y));
  }
  float wq0 = 0.f, wq1 = 0.f, cx0 = 0.f, cx1 = 0.f;
  if (wv < 4) {
    const float2 q = *(const float2*)(hidden + ((size_t)b * L_ + (L_ - 1)) * H_ + 2 * t256);
    wq0 = q.x; wq1 = q.y;
  }

  // ---- preloop: prefetch chunk NC-1 rows / X slice / d ----
  uint4 kr[4];
  float4 tA;
  float dv;
#pragma unroll
  for (int i = 0; i < 4; ++i)
    kr[i] = *(const uint4*)(khb + ((size_t)(NC - 1) * CA + 4 * wv + i) * H_ + 8 * lane);
  tA = *(const float4*)(tmb + (size_t)(NC - 1) * (CA * CA) + lane * CA + 4 * wv);
  dv = dvb[(NC - 1) * CA + lane];
  asm volatile("s_waitcnt vmcnt(0) lgkmcnt(0)\n\ts_barrier" ::: "memory");

  for (int c = NC - 1; c >= 0; --c) {
    // ---- prefetch chunk c-1 (global only) ----
    uint4 kn[4];
    float4 nA;
    float dN = 0.f;
    if (c > 0) {
#pragma unroll
      for (int i = 0; i < 4; ++i)
        kn[i] = *(const uint4*)(khb + ((size_t)(c - 1) * CA + 4 * wv + i) * H_ + 8 * lane);
      nA = *(const float4*)(tmb + (size_t)(c - 1) * (CA * CA) + lane * CA + 4 * wv);
      dN = dvb[(c - 1) * CA + lane];
    }

    // ---- dot: y[4wv+i] = K~[row].w via packed fp16 fma ----
    const uint4 wv4 = *(const uint4*)&Wsw16[4 * lane];
    float ysg[4];
#pragma unroll
    for (int i = 0; i < 4; ++i) {
      __half2 acc = __hmul2(u2h2(kr[i].x), u2h2(wv4.x));
      acc = __hfma2(u2h2(kr[i].y), u2h2(wv4.y), acc);
      acc = __hfma2(u2h2(kr[i].z), u2h2(wv4.z), acc);
      acc = __hfma2(u2h2(kr[i].w), u2h2(wv4.w), acc);
      const float2 pf = __half22float2(acc);
      float p = pf.x + pf.y;
      p = wave_reduce_lane63(p);
      ysg[i] = rdlane(p, 63);
    }

    // ---- sigma partial: sp[j=lane] = sum_i y[4wv+i] * X[j][4wv+i] ----
    float sp = ysg[0] * tA.x;
    sp = fmaf(ysg[1], tA.y, sp);
    sp = fmaf(ysg[2], tA.z, sp);
    sp = fmaf(ysg[3], tA.w, sp);
    Part2[lane * 17 + wv] = sp;
    asm volatile("s_waitcnt lgkmcnt(0)\n\ts_barrier" ::: "memory");  // b1

    // ---- sigma for this wave's 4 rows: 1 read + DPP row16 + readlane ----
    float red = Part2[(4 * wv + (lane >> 4)) * 17 + (lane & 15)];
    red = row16_reduce(red);
    const float sg0 = rdlane(red, 15);
    const float sg1 = rdlane(red, 31);
    const float sg2 = rdlane(red, 47);
    const float sg3 = rdlane(red, 63);
    const float sv0 = sg0 * rdlane(dv, 4 * wv + 0);
    const float sv1 = sg1 * rdlane(dv, 4 * wv + 1);
    const float sv2 = sg2 * rdlane(dv, 4 * wv + 2);
    const float sv3 = sg3 * rdlane(dv, 4 * wv + 3);

    // ---- update partials in packed fp16 (lane owns h = 8*lane..8*lane+7) ----
    {
      const __half2 g0 = __float2half2_rn(sg0), g1 = __float2half2_rn(sg1);
      const __half2 g2 = __float2half2_rn(sg2), g3 = __float2half2_rn(sg3);
      const __half2 v0 = __float2half2_rn(sv0), v1 = __float2half2_rn(sv1);
      const __half2 v2 = __float2half2_rn(sv2), v3 = __float2half2_rn(sv3);
      uint4 wsu, csu;
      {
        __half2 a, bqq;
        // word x
        a = __hmul2(g0, u2h2(kr[0].x)); a = __hfma2(g1, u2h2(kr[1].x), a);
        a = __hfma2(g2, u2h2(kr[2].x), a); a = __hfma2(g3, u2h2(kr[3].x), a);
        wsu.x = h22u(a);
        bqq = __hmul2(v0, u2h2(kr[0].x)); bqq = __hfma2(v1, u2h2(kr[1].x), bqq);
        bqq = __hfma2(v2, u2h2(kr[2].x), bqq); bqq = __hfma2(v3, u2h2(kr[3].x), bqq);
        csu.x = h22u(bqq);
        // word y
        a = __hmul2(g0, u2h2(kr[0].y)); a = __hfma2(g1, u2h2(kr[1].y), a);
        a = __hfma2(g2, u2h2(kr[2].y), a); a = __hfma2(g3, u2h2(kr[3].y), a);
        wsu.y = h22u(a);
        bqq = __hmul2(v0, u2h2(kr[0].y)); bqq = __hfma2(v1, u2h2(kr[1].y), bqq);
        bqq = __hfma2(v2, u2h2(kr[2].y), bqq); bqq = __hfma2(v3, u2h2(kr[3].y), bqq);
        csu.y = h22u(bqq);
        // word z
        a = __hmul2(g0, u2h2(kr[0].z)); a = __hfma2(g1, u2h2(kr[1].z), a);
        a = __hfma2(g2, u2h2(kr[2].z), a); a = __hfma2(g3, u2h2(kr[3].z), a);
        wsu.z = h22u(a);
        bqq = __hmul2(v0, u2h2(kr[0].z)); bqq = __hfma2(v1, u2h2(kr[1].z), bqq);
        bqq = __hfma2(v2, u2h2(kr[2].z), bqq); bqq = __hfma2(v3, u2h2(kr[3].z), bqq);
        csu.z = h22u(bqq);
        // word w
        a = __hmul2(g0, u2h2(kr[0].w)); a = __hfma2(g1, u2h2(kr[1].w), a);
        a = __hfma2(g2, u2h2(kr[2].w), a); a = __hfma2(g3, u2h2(kr[3].w), a);
        wsu.w = h22u(a);
        bqq = __hmul2(v0, u2h2(kr[0].w)); bqq = __hfma2(v1, u2h2(kr[1].w), bqq);
        bqq = __hfma2(v2, u2h2(kr[2].w), bqq); bqq = __hfma2(v3, u2h2(kr[3].w), bqq);
        csu.w = h22u(bqq);
      }
      *(uint4*)&PartU16[wv][4 * lane]       = wsu;  // conflict-free b128
      *(uint4*)&PartU16[wv][256 + 4 * lane] = csu;
    }
    asm volatile("s_waitcnt lgkmcnt(0)\n\ts_barrier" ::: "memory");  // b2

    // ---- combine: conflict-free (word t across lanes is consecutive) ----
    if (wv < 4) {          // w: subtract from f32 master, publish fp16
      __half2 s = u2h2(PartU16[0][t256]);
#pragma unroll
      for (int w2 = 1; w2 < 16; ++w2) s = __hadd2(s, u2h2(PartU16[w2][t256]));
      const float2 sf = __half22float2(s);
      wq0 -= sf.x; wq1 -= sf.y;
      Wsw16[t256] = h22u(__floats2half2_rn(wq0, wq1));
    } else if (wv < 8) {   // ctx: accumulate f32 in registers
      __half2 s = u2h2(PartU16[0][256 + t256]);
#pragma unroll
      for (int w2 = 1; w2 < 16; ++w2) s = __hadd2(s, u2h2(PartU16[w2][256 + t256]));
      const float2 sf = __half22float2(s);
      cx0 += sf.x; cx1 += sf.y;
    }

    // rotate prefetched regs
    if (c > 0) {
      dv = dN; tA = nA;
#pragma unroll
      for (int i = 0; i < 4; ++i) kr[i] = kn[i];
    }
    asm volatile("s_waitcnt vmcnt(0) lgkmcnt(0)\n\ts_barrier" ::: "memory");  // b3
  }

  // ---- epilogue: out[b] = W @ ctx + bias ----
  if (wv >= 4 && wv < 8) *(float2*)&Ctx[2 * t256] = make_float2(cx0, cx1);
  __syncthreads();
  {
    float* Ep = (float*)&PartU16[0][0];
    const int o = tid & (H_ - 1);
    const int hf = tid >> 9;
    float acc = 0.f;
    const float* wr = Wm + (size_t)o * H_ + hf * 256;
    const float* cx = &Ctx[hf * 256];
#pragma unroll 8
    for (int i = 0; i < 256; i += 4) {
      const float4 w4 = *(const float4*)(wr + i);
      const float4 cv = *(const float4*)(cx + i);
      acc = fmaf(w4.x, cv.x, acc); acc = fmaf(w4.y, cv.y, acc);
      acc = fmaf(w4.z, cv.z, acc); acc = fmaf(w4.w, cv.w, acc);
    }
    Ep[hf * 512 + o] = acc;
    __syncthreads();
    if (tid < H_) out[(size_t)b * H_ + tid] = Ep[tid] + Ep[512 + tid] + bias[tid];
  }
}

// =====================================================================
extern "C" void kernel_launch(void* const* d_in, const int* in_sizes, int n_in,
                              void* d_out, int out_size, void* d_ws, size_t ws_size,
                              hipStream_t stream) {
  (void)in_sizes; (void)n_in; (void)out_size; (void)ws_size;
  const float* hidden = (const float*)d_in[0];  // (32, 2048, 512) fp32
  const float* Wm     = (const float*)d_in[1];  // (512, 512) fp32
  const float* bias   = (const float*)d_in[2];  // (512,) fp32
  float* out = (float*)d_out;                   // (32, 512) fp32

  // workspace: Kh 64 MB + tmT 16 MB (fp32) + dvec 256 KB
  const size_t szKh = (size_t)B_ * L_ * H_ * sizeof(unsigned short);
  unsigned short* Kh = (unsigned short*)d_ws;
  float* tmT  = (float*)((char*)d_ws + szKh);
  float* dvec = tmT + (size_t)B_ * NC * CA * CA;

  deltarule_gram64<<<dim3(NC, B_), 256, 0, stream>>>(hidden, Kh, tmT, dvec);
  deltarule_scan16<<<B_, 1024, 0, stream>>>(hidden, Kh, Wm, bias, tmT, dvec, out);
}